// Round 16
// baseline (615.459 us; speedup 1.0000x reference)
//
#include <hip/hip_runtime.h>
#include <hip/hip_bf16.h>

typedef __bf16 bf16;
typedef __bf16 bf16x4 __attribute__((ext_vector_type(4)));
typedef __bf16 bf16x8 __attribute__((ext_vector_type(8)));
typedef float f32x4 __attribute__((ext_vector_type(4)));
typedef unsigned int u32x4 __attribute__((ext_vector_type(4)));

#define NB 16
#define NS 729
#define ND 1152
#define NDP 1280        /* 5*256: padded N for v-proj / fc2 outputs */
#define NH 16
#define NHD 72
#define NI 4304
#define NM (NB*NS)      /* 11664 */
#define MP 11776        /* 92*128 */
#define NIP 4352        /* 17*256 */
#define NQ (ND/4)       /* 288 quads per row */
#define OUT0 ((size_t)NM*(size_t)ND)
#define LNEPS 1e-6f
#define EPS_STRIDE 264  /* epilogue LDS row stride (bf16 elems) */

#define GLOAD16(gp, lp) __builtin_amdgcn_global_load_lds( \
    (const __attribute__((address_space(1))) void*)(gp),  \
    (__attribute__((address_space(3))) void*)(lp), 16, 0, 0)

static __device__ __forceinline__ void nt_store_f32(float v, float* p) {
  __builtin_nontemporal_store(v, p);
}

// ---------------- weight conversions ----------------
__global__ __launch_bounds__(256) void k_conv_w(const float* __restrict__ src,
                                                bf16* __restrict__ dst,
                                                int sR, int sC, int dR, int dC) {
  int idx = blockIdx.x * 256 + threadIdx.x;
  int rowlen = dC >> 2;
  int r = idx / rowlen;
  int c = (idx - r * rowlen) * 4;
  if (r >= dR) return;
  bf16x4 o;
  if (r < sR && c + 4 <= sC) {
    float4 v = *(const float4*)(&src[(size_t)r * sC + c]);
    o[0] = (bf16)v.x; o[1] = (bf16)v.y; o[2] = (bf16)v.z; o[3] = (bf16)v.w;
  } else {
    o[0] = (bf16)0.f; o[1] = (bf16)0.f; o[2] = (bf16)0.f; o[3] = (bf16)0.f;
  }
  *(bf16x4*)(&dst[(size_t)r * dC + c]) = o;
}

// ---------------- q = Wq @ probe + bq ----------------
__global__ __launch_bounds__(256) void k_q(const float* __restrict__ Wq,
                                           const float* __restrict__ probe,
                                           const float* __restrict__ bq,
                                           float* __restrict__ q) {
  int d = blockIdx.x;
  const float* wrow = Wq + (size_t)d * ND;
  float s = 0.f;
  for (int e = threadIdx.x; e < ND; e += 256) s += wrow[e] * probe[e];
  for (int o = 32; o; o >>= 1) s += __shfl_down(s, o, 64);
  __shared__ float sm[4];
  if ((threadIdx.x & 63) == 0) sm[threadIdx.x >> 6] = s;
  __syncthreads();
  if (threadIdx.x == 0) q[d] = sm[0] + sm[1] + sm[2] + sm[3] + bq[d];
}

// ---------------- qk[h,e] = sum_j q[h*72+j]*Wk[h*72+j, e]  (scaled) ----------------
__global__ __launch_bounds__(256) void k_qk(const float* __restrict__ Wk,
                                            const float* __restrict__ bk,
                                            const float* __restrict__ q,
                                            float* __restrict__ qk,
                                            float* __restrict__ qb) {
  int idx = blockIdx.x * 256 + threadIdx.x;
  if (idx >= NH * ND) return;
  int h = idx / ND, e = idx - h * ND;
  const float scale = 0.11785113019775793f;  // 1/sqrt(72)
  float s = 0.f;
  for (int j = 0; j < NHD; ++j)
    s += q[h * NHD + j] * Wk[(size_t)(h * NHD + j) * ND + e];
  qk[idx] = s * scale;
  if (e == 0) {
    float sb = 0.f;
    for (int j = 0; j < NHD; ++j) sb += q[h * NHD + j] * bk[h * NHD + j];
    qb[h] = sb * scale;
  }
}

// ------- scores[b,h,s] = hs[b,s,:]·qk[h,:] + qb[h]; also emit hsb (bf16) -------
__global__ __launch_bounds__(256) void k_scores(const float* __restrict__ hs,
                                                const float* __restrict__ qk,
                                                const float* __restrict__ qb,
                                                float* __restrict__ attn,
                                                bf16* __restrict__ hsb) {
  int p = blockIdx.x;                 // (b*S + s)
  int t = threadIdx.x;
  bf16x4* orow4 = (bf16x4*)(hsb + (size_t)p * ND);
  if (p >= NM) {
    bf16x4 z;
    z[0] = (bf16)0.f; z[1] = (bf16)0.f; z[2] = (bf16)0.f; z[3] = (bf16)0.f;
    for (int i = t; i < NQ; i += 256) orow4[i] = z;
    return;
  }
  const f32x4* row4 = (const f32x4*)(hs + (size_t)p * ND);
  const f32x4* qk4 = (const f32x4*)qk;
  float acc[NH];
#pragma unroll
  for (int h = 0; h < NH; ++h) acc[h] = 0.f;
  for (int i = t; i < NQ; i += 256) {
    f32x4 x = __builtin_nontemporal_load(&row4[i]);
    bf16x4 o;
    o[0] = (bf16)x[0]; o[1] = (bf16)x[1]; o[2] = (bf16)x[2]; o[3] = (bf16)x[3];
    orow4[i] = o;
#pragma unroll
    for (int h = 0; h < NH; ++h) {
      f32x4 wv = qk4[h * NQ + i];
      acc[h] = fmaf(x[0], wv[0],
               fmaf(x[1], wv[1], fmaf(x[2], wv[2], fmaf(x[3], wv[3], acc[h]))));
    }
  }
  __shared__ float part[NH][257];
#pragma unroll
  for (int h = 0; h < NH; ++h) part[h][t] = acc[h];
  __syncthreads();
  int h = t >> 4, l = t & 15;
  float s = 0.f;
#pragma unroll
  for (int k = 0; k < 16; ++k) s += part[h][l + k * 16];
#pragma unroll
  for (int o = 8; o; o >>= 1) s += __shfl_xor(s, o, 16);
  if (l == 0) {
    int b = p / NS, si = p - b * NS;
    attn[((size_t)(b * NH + h)) * NS + si] = s + qb[h];
  }
}

// ---------------- softmax over S for each (b,h) row, in place ----------------
__global__ __launch_bounds__(256) void k_softmax(float* __restrict__ attn) {
  float* a = attn + (size_t)blockIdx.x * NS;
  int t = threadIdx.x;
  float x0 = (t < NS) ? a[t] : -1e30f;
  float x1 = (t + 256 < NS) ? a[t + 256] : -1e30f;
  float x2 = (t + 512 < NS) ? a[t + 512] : -1e30f;
  float mx = fmaxf(x0, fmaxf(x1, x2));
  for (int o = 32; o; o >>= 1) mx = fmaxf(mx, __shfl_down(mx, o, 64));
  __shared__ float sm[4], sm2[4];
  if ((t & 63) == 0) sm[t >> 6] = mx;
  __syncthreads();
  mx = fmaxf(fmaxf(sm[0], sm[1]), fmaxf(sm[2], sm[3]));
  float e0 = (t < NS) ? __expf(x0 - mx) : 0.f;
  float e1 = (t + 256 < NS) ? __expf(x1 - mx) : 0.f;
  float e2 = (t + 512 < NS) ? __expf(x2 - mx) : 0.f;
  float s = e0 + e1 + e2;
  for (int o = 32; o; o >>= 1) s += __shfl_down(s, o, 64);
  if ((t & 63) == 0) sm2[t >> 6] = s;
  __syncthreads();
  float inv = 1.f / (sm2[0] + sm2[1] + sm2[2] + sm2[3]);
  if (t < NS) a[t] = e0 * inv;
  if (t + 256 < NS) a[t + 256] = e1 * inv;
  if (t + 512 < NS) a[t + 512] = e2 * inv;
}

// ------- layernorm rows of v(bf16) -> bf16 vn; vectorized, regular loads -----
__global__ __launch_bounds__(256) void k_ln(const bf16* __restrict__ v,
                                            const float* __restrict__ lw,
                                            const float* __restrict__ lb,
                                            bf16* __restrict__ vn) {
  int r = blockIdx.x;
  int t = threadIdx.x;
  bf16x4* vn4 = (bf16x4*)(vn + (size_t)r * ND);
  if (r >= NM) {
    bf16x4 z;
    z[0] = (bf16)0.f; z[1] = (bf16)0.f; z[2] = (bf16)0.f; z[3] = (bf16)0.f;
    for (int i = t; i < NQ; i += 256) vn4[i] = z;
    return;
  }
  const bf16x4* row4 = (const bf16x4*)(v + (size_t)r * ND);
  bf16x4 b0 = row4[t];
  f32x4 x0 = {(float)b0[0], (float)b0[1], (float)b0[2], (float)b0[3]};
  f32x4 x1 = {0.f, 0.f, 0.f, 0.f};
  const bool has1 = (t + 256) < NQ;
  if (has1) {
    bf16x4 b1 = row4[t + 256];
    x1[0] = (float)b1[0]; x1[1] = (float)b1[1];
    x1[2] = (float)b1[2]; x1[3] = (float)b1[3];
  }
  float s = x0[0] + x0[1] + x0[2] + x0[3] + x1[0] + x1[1] + x1[2] + x1[3];
  float sq = x0[0] * x0[0] + x0[1] * x0[1] + x0[2] * x0[2] + x0[3] * x0[3] +
             x1[0] * x1[0] + x1[1] * x1[1] + x1[2] * x1[2] + x1[3] * x1[3];
  for (int o = 32; o; o >>= 1) {
    s += __shfl_down(s, o, 64);
    sq += __shfl_down(sq, o, 64);
  }
  __shared__ float smS[4], smQ[4];
  if ((t & 63) == 0) { smS[t >> 6] = s; smQ[t >> 6] = sq; }
  __syncthreads();
  s = smS[0] + smS[1] + smS[2] + smS[3];
  sq = smQ[0] + smQ[1] + smQ[2] + smQ[3];
  float mu = s * (1.f / ND);
  float var = sq * (1.f / ND) - mu * mu;
  float rstd = rsqrtf(var + LNEPS);
  const f32x4* lw4 = (const f32x4*)lw;
  const f32x4* lb4 = (const f32x4*)lb;
  {
    f32x4 wv = lw4[t], bv = lb4[t];
    bf16x4 o;
    o[0] = (bf16)((x0[0] - mu) * rstd * wv[0] + bv[0]);
    o[1] = (bf16)((x0[1] - mu) * rstd * wv[1] + bv[1]);
    o[2] = (bf16)((x0[2] - mu) * rstd * wv[2] + bv[2]);
    o[3] = (bf16)((x0[3] - mu) * rstd * wv[3] + bv[3]);
    vn4[t] = o;
  }
  if (has1) {
    f32x4 wv = lw4[t + 256], bv = lb4[t + 256];
    bf16x4 o;
    o[0] = (bf16)((x1[0] - mu) * rstd * wv[0] + bv[0]);
    o[1] = (bf16)((x1[1] - mu) * rstd * wv[1] + bv[1]);
    o[2] = (bf16)((x1[2] - mu) * rstd * wv[2] + bv[2]);
    o[3] = (bf16)((x1[3] - mu) * rstd * wv[3] + bv[3]);
    vn4[t + 256] = o;
  }
}

// ==== 128x256xBK32, 8-wave, 2 blocks/CU, 3-buffer counted-vmcnt GEMM ====
// R16: MODE 1 epilogue now repacks gelu output through the (dead) K-loop LDS
// and emits full-64B-line NON-TEMPORAL stores — kills L2 write-allocate and
// L3 eviction by the 100 MB h1b write stream (fc1's 89 MB excess FETCH).
// MODE 0 (vb) keeps plain cached stores (consumed by k_ln/fc2 — R13 lesson).
template <int MODE>
__global__ __launch_bounds__(512, 4) void gemm128(const bf16* __restrict__ A,
                                                  const bf16* __restrict__ Bm,
                                                  const float* __restrict__ bias,
                                                  const bf16* __restrict__ resid,
                                                  float* __restrict__ Cf,
                                                  bf16* __restrict__ Cb,
                                                  int K, int Mreal, int Nreal,
                                                  int ldc, int gx, int G) {
  __shared__ bf16 lds[3][384 * 32];   // [buf][A:128 rows | B:256 rows][32 k]
  const int tid = threadIdx.x;
  const int w = tid >> 6, lane = tid & 63;

  // T1: bijective XCD-aware block swizzle (m204)
  const int nwg = gridDim.x;
  const int orig = blockIdx.x;
  const int qq = nwg >> 3, rr = nwg & 7;
  const int xcd = orig & 7, idx0 = orig >> 3;
  const int wgid = (xcd < rr ? xcd * (qq + 1) : rr * (qq + 1) + (xcd - rr) * qq) + idx0;

  // grouped decode: G rows per group, column-major within group (R13 best)
  const int gy = nwg / gx;
  const int full = (gy / G) * G * gx;
  int bx, by;
  if (wgid < full) {
    int g = wgid / (G * gx), r2 = wgid - g * (G * gx);
    bx = r2 / G; by = g * G + (r2 - bx * G);
  } else {
    int r2 = wgid - full;
    int base = (gy / G) * G, rows = gy - base;
    bx = r2 / rows; by = base + (r2 - bx * rows);
  }
  const int row0 = by * 128, col0 = bx * 256;

  // staging: wave w covers 16 rows (lane>>2), chunk lane&3 at LDS (linear);
  // global source chunk = (lane&3) ^ ((lane>>3)&3)
  const int laneRow = lane >> 2;
  const int laneChunk = (lane & 3) ^ ((lane >> 3) & 3);

  auto STAGE_A = [&](int buf, int kt) {   // A tile 128x32 = 8 KB, 1 load/thread
    const bf16* gp = A + (size_t)(row0 + w * 16 + laneRow) * K + kt * 32 + laneChunk * 8;
    GLOAD16(gp, &lds[buf][(w * 16) * 32]);
  };
  auto STAGE_B = [&](int buf, int u, int kt) {  // B half-tile 128x32 = 8 KB
    const bf16* gp = Bm + (size_t)(col0 + u * 128 + w * 16 + laneRow) * K + kt * 32 + laneChunk * 8;
    GLOAD16(gp, &lds[buf][4096 + (u * 128 + w * 16) * 32]);
  };

  // fragment addressing (16x16x32: row = fr, k-chunk = fq, swizzled)
  const int wm = w >> 2, wn = w & 3;
  const int fr = lane & 15, fq = lane >> 4;
  const int fsw = ((fq ^ ((fr >> 1) & 3)) << 3);   // swizzled k-offset (elems)
  const int arow = wm * 64 + fr;
  const int brow = wn * 64 + fr;

  f32x4 acc[4][4] = {};

  const int nk = K >> 5;
  // ---- prologue: tiles 0,1 staged; wait tile0 only (tile1 in flight) ----
  STAGE_A(0, 0); STAGE_B(0, 0, 0); STAGE_B(0, 1, 0);
  if (nk > 1) {
    STAGE_A(1, 1); STAGE_B(1, 0, 1); STAGE_B(1, 1, 1);
    asm volatile("s_waitcnt vmcnt(3)" ::: "memory");
  } else {
    asm volatile("s_waitcnt vmcnt(0)" ::: "memory");
  }
  __builtin_amdgcn_s_barrier();

  int cur = 0;
  for (int t = 0; t < nk; ++t) {
    const bf16* As = &lds[cur][0];
    const bf16* Bs = &lds[cur][4096];
    // issue tile t+2's staging into the buffer consumed at t-1
    if (t + 2 < nk) {
      int tgt = cur + 2; if (tgt >= 3) tgt -= 3;
      STAGE_A(tgt, t + 2);
      STAGE_B(tgt, 0, t + 2);
      STAGE_B(tgt, 1, t + 2);
    }
    bf16x8 bfr[4];
#pragma unroll
    for (int ni = 0; ni < 4; ++ni)
      bfr[ni] = *(const bf16x8*)(&Bs[(brow + ni * 16) * 32 + fsw]);
    __builtin_amdgcn_s_setprio(1);
#pragma unroll
    for (int mi = 0; mi < 4; ++mi) {
      bf16x8 af = *(const bf16x8*)(&As[(arow + mi * 16) * 32 + fsw]);
#pragma unroll
      for (int ni = 0; ni < 4; ++ni)
        acc[mi][ni] = __builtin_amdgcn_mfma_f32_16x16x32_bf16(af, bfr[ni],
                                                              acc[mi][ni], 0, 0, 0);
    }
    __builtin_amdgcn_s_setprio(0);
    if (t + 2 < nk)      { asm volatile("s_waitcnt vmcnt(3)" ::: "memory"); }
    else if (t + 1 < nk) { asm volatile("s_waitcnt vmcnt(0)" ::: "memory"); }
    __builtin_amdgcn_s_barrier();
    cur += 1; if (cur >= 3) cur -= 3;
  }

  // ---- epilogue ----
  const int rb = row0 + wm * 64, cb = col0 + wn * 64;
  if (MODE == 1) {
    // gelu -> LDS repack (row stride EPS_STRIDE) -> full-line NT stores.
    // K-loop LDS is dead (final loop barrier passed; all reads in regs).
    bf16* ep = (bf16*)lds;            // 128 x 264 bf16 = 67.5 KB <= 72 KB
    __syncthreads();
#pragma unroll
    for (int mi = 0; mi < 4; ++mi) {
#pragma unroll
      for (int ni = 0; ni < 4; ++ni) {
        int cl = wn * 64 + ni * 16 + fr;        // block-local col
        int cg = col0 + cl;                     // global col
        float bb = (cg < Nreal) ? bias[cg] : 0.f;
#pragma unroll
        for (int j = 0; j < 4; ++j) {
          int rl = wm * 64 + mi * 16 + fq * 4 + j;  // block-local row
          float g = 0.f;
          if (cg < Nreal) {
            float x = acc[mi][ni][j] + bb;
            float z = 1.5957691216057308f * (x + 0.044715f * x * x * x);
            g = x / (1.f + __expf(-z));
          }
          ep[rl * EPS_STRIDE + cl] = (bf16)g;
        }
      }
    }
    __syncthreads();
    // readback: thread t -> row t>>2, 64-col chunk (t&3); 8 x 16B NT stores
    int rl = tid >> 2, cc = (tid & 3) * 64;
    bf16* gdst = Cb + (size_t)(row0 + rl) * ldc + col0 + cc;
    const bf16* lsrc = &ep[rl * EPS_STRIDE + cc];
#pragma unroll
    for (int i = 0; i < 8; ++i) {
      bf16x8 vv = *(const bf16x8*)(&lsrc[i * 8]);
      u32x4 uu;
      __builtin_memcpy(&uu, &vv, 16);
      __builtin_nontemporal_store(uu, (u32x4*)(&gdst[i * 8]));
    }
  } else {
#pragma unroll
    for (int mi = 0; mi < 4; ++mi) {
#pragma unroll
      for (int ni = 0; ni < 4; ++ni) {
        int c = cb + ni * 16 + fr;
#pragma unroll
        for (int j = 0; j < 4; ++j) {
          int r = rb + mi * 16 + fq * 4 + j;
          float v = acc[mi][ni][j];
          if (MODE == 0) {
            if (r < Mreal && c < Nreal)
              Cb[(size_t)r * ldc + c] = (bf16)(v + bias[c]);
          } else {
            if (r < Mreal && c < Nreal)
              nt_store_f32(v + bias[c] + (float)resid[(size_t)r * ldc + c],
                           &Cf[(size_t)r * ldc + c]);
          }
        }
      }
    }
  }
}

extern "C" void kernel_launch(void* const* d_in, const int* in_sizes, int n_in,
                              void* d_out, int out_size, void* d_ws, size_t ws_size,
                              hipStream_t stream) {
  const float* hs    = (const float*)d_in[0];
  const float* probe = (const float*)d_in[1];
  const float* ipw   = (const float*)d_in[2];
  const float* ipb   = (const float*)d_in[3];
  const float* lw    = (const float*)d_in[4];
  const float* lb    = (const float*)d_in[5];
  const float* fc1w  = (const float*)d_in[6];
  const float* fc1b  = (const float*)d_in[7];
  const float* fc2w  = (const float*)d_in[8];
  const float* fc2b  = (const float*)d_in[9];
  float* out  = (float*)d_out;
  float* attn = out + OUT0;

  char* ws = (char*)d_ws;
  size_t off = 0;
  auto alloc = [&](size_t bytes) {
    char* p = ws + off;
    off += (bytes + 255) & ~(size_t)255;
    return p;
  };
  float* q  = (float*)alloc((size_t)ND * 4);
  float* qk = (float*)alloc((size_t)NH * ND * 4);
  float* qb = (float*)alloc((size_t)NH * 4);
  bf16* hsb = (bf16*)alloc((size_t)MP * ND * 2);   // doubles as vnb after v-proj
  bf16* vb  = (bf16*)alloc((size_t)MP * ND * 2);   // v in bf16
  bf16* wvb = (bf16*)alloc((size_t)NDP * ND * 2);
  bf16* f1b = (bf16*)alloc((size_t)NIP * ND * 2);
  bf16* f2b = (bf16*)alloc((size_t)NDP * NIP * 2);
  bf16* h1b = (bf16*)alloc((size_t)MP * NIP * 2);
  bf16* vnb = hsb;   // alias: hsb is dead after v-proj; k_ln runs after

  // weight conversions to bf16 (zero-padded)
  k_conv_w<<<(NDP * (ND / 4) + 255) / 256, 256, 0, stream>>>(
      ipw + (size_t)2 * ND * ND, wvb, ND, ND, NDP, ND);
  k_conv_w<<<(NIP * (ND / 4) + 255) / 256, 256, 0, stream>>>(
      fc1w, f1b, NI, ND, NIP, ND);
  k_conv_w<<<(NDP * (NIP / 4) + 255) / 256, 256, 0, stream>>>(
      fc2w, f2b, ND, NI, NDP, NIP);

  // attention scores path (f32, exact) — k_scores also emits hsb (bf16,
  // rows >= NM zeroed in-kernel)
  k_q<<<ND, 256, 0, stream>>>(ipw, probe, ipb, q);
  k_qk<<<(NH * ND + 255) / 256, 256, 0, stream>>>(
      ipw + (size_t)ND * ND, ipb + ND, q, qk, qb);
  k_scores<<<MP, 256, 0, stream>>>(hs, qk, qb, attn, hsb);
  k_softmax<<<NB * NH, 256, 0, stream>>>(attn);

  // v = hs @ Wv^T + bv  -> bf16 vb          (grid 92x5, G=8 row groups)
  gemm128<0><<<(MP / 128) * (NDP / 256), 512, 0, stream>>>(
      hsb, wvb, ipb + 2 * ND, nullptr, nullptr, vb, ND, NM, ND, ND,
      NDP / 256, 8);
  // vn = LN(vb) -> bf16 (into hsb's buffer)
  k_ln<<<MP, 256, 0, stream>>>(vb, lw, lb, vnb);
  // h1 = gelu(vn @ fc1^T + b1) -> bf16      (grid 92x17, G=8)
  gemm128<1><<<(MP / 128) * (NIP / 256), 512, 0, stream>>>(
      vnb, f1b, fc1b, nullptr, nullptr, h1b, ND, MP, NI, NIP, NIP / 256, 8);
  // out = vb + h1 @ fc2^T + b2              (grid 92x5, G=2)
  gemm128<2><<<(MP / 128) * (NDP / 256), 512, 0, stream>>>(
      h1b, f2b, fc2b, vb, out, nullptr, NIP, NM, ND, ND, NDP / 256, 2);
}

// Round 17
// 468.003 us; speedup vs baseline: 1.3151x; 1.3151x over previous
//
#include <hip/hip_runtime.h>
#include <hip/hip_bf16.h>

typedef __bf16 bf16;
typedef __bf16 bf16x4 __attribute__((ext_vector_type(4)));
typedef __bf16 bf16x8 __attribute__((ext_vector_type(8)));
typedef float f32x4 __attribute__((ext_vector_type(4)));
typedef unsigned int u32x4 __attribute__((ext_vector_type(4)));

#define NB 16
#define NS 729
#define ND 1152
#define NDP 1280        /* 5*256: padded N for v-proj / fc2 outputs */
#define NH 16
#define NHD 72
#define NI 4304
#define NM (NB*NS)      /* 11664 */
#define MP 11776        /* 92*128 */
#define NIP 4352        /* 17*256 */
#define NQ (ND/4)       /* 288 quads per row */
#define OUT0 ((size_t)NM*(size_t)ND)
#define LNEPS 1e-6f
#define EPS_STRIDE 264  /* epilogue LDS row stride (bf16 elems) */

#define GLOAD16(gp, lp) __builtin_amdgcn_global_load_lds( \
    (const __attribute__((address_space(1))) void*)(gp),  \
    (__attribute__((address_space(3))) void*)(lp), 16, 0, 0)

static __device__ __forceinline__ void nt_store_f32(float v, float* p) {
  __builtin_nontemporal_store(v, p);
}

// ---------------- weight conversions ----------------
__global__ __launch_bounds__(256) void k_conv_w(const float* __restrict__ src,
                                                bf16* __restrict__ dst,
                                                int sR, int sC, int dR, int dC) {
  int idx = blockIdx.x * 256 + threadIdx.x;
  int rowlen = dC >> 2;
  int r = idx / rowlen;
  int c = (idx - r * rowlen) * 4;
  if (r >= dR) return;
  bf16x4 o;
  if (r < sR && c + 4 <= sC) {
    float4 v = *(const float4*)(&src[(size_t)r * sC + c]);
    o[0] = (bf16)v.x; o[1] = (bf16)v.y; o[2] = (bf16)v.z; o[3] = (bf16)v.w;
  } else {
    o[0] = (bf16)0.f; o[1] = (bf16)0.f; o[2] = (bf16)0.f; o[3] = (bf16)0.f;
  }
  *(bf16x4*)(&dst[(size_t)r * dC + c]) = o;
}

// ---------------- q = Wq @ probe + bq ----------------
__global__ __launch_bounds__(256) void k_q(const float* __restrict__ Wq,
                                           const float* __restrict__ probe,
                                           const float* __restrict__ bq,
                                           float* __restrict__ q) {
  int d = blockIdx.x;
  const float* wrow = Wq + (size_t)d * ND;
  float s = 0.f;
  for (int e = threadIdx.x; e < ND; e += 256) s += wrow[e] * probe[e];
  for (int o = 32; o; o >>= 1) s += __shfl_down(s, o, 64);
  __shared__ float sm[4];
  if ((threadIdx.x & 63) == 0) sm[threadIdx.x >> 6] = s;
  __syncthreads();
  if (threadIdx.x == 0) q[d] = sm[0] + sm[1] + sm[2] + sm[3] + bq[d];
}

// ---------------- qk[h,e] = sum_j q[h*72+j]*Wk[h*72+j, e]  (scaled) ----------------
__global__ __launch_bounds__(256) void k_qk(const float* __restrict__ Wk,
                                            const float* __restrict__ bk,
                                            const float* __restrict__ q,
                                            float* __restrict__ qk,
                                            float* __restrict__ qb) {
  int idx = blockIdx.x * 256 + threadIdx.x;
  if (idx >= NH * ND) return;
  int h = idx / ND, e = idx - h * ND;
  const float scale = 0.11785113019775793f;  // 1/sqrt(72)
  float s = 0.f;
  for (int j = 0; j < NHD; ++j)
    s += q[h * NHD + j] * Wk[(size_t)(h * NHD + j) * ND + e];
  qk[idx] = s * scale;
  if (e == 0) {
    float sb = 0.f;
    for (int j = 0; j < NHD; ++j) sb += q[h * NHD + j] * bk[h * NHD + j];
    qb[h] = sb * scale;
  }
}

// ------- scores[b,h,s] = hs[b,s,:]·qk[h,:] + qb[h]; also emit hsb (bf16) -------
__global__ __launch_bounds__(256) void k_scores(const float* __restrict__ hs,
                                                const float* __restrict__ qk,
                                                const float* __restrict__ qb,
                                                float* __restrict__ attn,
                                                bf16* __restrict__ hsb) {
  int p = blockIdx.x;                 // (b*S + s)
  int t = threadIdx.x;
  bf16x4* orow4 = (bf16x4*)(hsb + (size_t)p * ND);
  if (p >= NM) {
    bf16x4 z;
    z[0] = (bf16)0.f; z[1] = (bf16)0.f; z[2] = (bf16)0.f; z[3] = (bf16)0.f;
    for (int i = t; i < NQ; i += 256) orow4[i] = z;
    return;
  }
  const f32x4* row4 = (const f32x4*)(hs + (size_t)p * ND);
  const f32x4* qk4 = (const f32x4*)qk;
  float acc[NH];
#pragma unroll
  for (int h = 0; h < NH; ++h) acc[h] = 0.f;
  for (int i = t; i < NQ; i += 256) {
    f32x4 x = __builtin_nontemporal_load(&row4[i]);
    bf16x4 o;
    o[0] = (bf16)x[0]; o[1] = (bf16)x[1]; o[2] = (bf16)x[2]; o[3] = (bf16)x[3];
    orow4[i] = o;
#pragma unroll
    for (int h = 0; h < NH; ++h) {
      f32x4 wv = qk4[h * NQ + i];
      acc[h] = fmaf(x[0], wv[0],
               fmaf(x[1], wv[1], fmaf(x[2], wv[2], fmaf(x[3], wv[3], acc[h]))));
    }
  }
  __shared__ float part[NH][257];
#pragma unroll
  for (int h = 0; h < NH; ++h) part[h][t] = acc[h];
  __syncthreads();
  int h = t >> 4, l = t & 15;
  float s = 0.f;
#pragma unroll
  for (int k = 0; k < 16; ++k) s += part[h][l + k * 16];
#pragma unroll
  for (int o = 8; o; o >>= 1) s += __shfl_xor(s, o, 16);
  if (l == 0) {
    int b = p / NS, si = p - b * NS;
    attn[((size_t)(b * NH + h)) * NS + si] = s + qb[h];
  }
}

// ---------------- softmax over S for each (b,h) row, in place ----------------
__global__ __launch_bounds__(256) void k_softmax(float* __restrict__ attn) {
  float* a = attn + (size_t)blockIdx.x * NS;
  int t = threadIdx.x;
  float x0 = (t < NS) ? a[t] : -1e30f;
  float x1 = (t + 256 < NS) ? a[t + 256] : -1e30f;
  float x2 = (t + 512 < NS) ? a[t + 512] : -1e30f;
  float mx = fmaxf(x0, fmaxf(x1, x2));
  for (int o = 32; o; o >>= 1) mx = fmaxf(mx, __shfl_down(mx, o, 64));
  __shared__ float sm[4], sm2[4];
  if ((t & 63) == 0) sm[t >> 6] = mx;
  __syncthreads();
  mx = fmaxf(fmaxf(sm[0], sm[1]), fmaxf(sm[2], sm[3]));
  float e0 = (t < NS) ? __expf(x0 - mx) : 0.f;
  float e1 = (t + 256 < NS) ? __expf(x1 - mx) : 0.f;
  float e2 = (t + 512 < NS) ? __expf(x2 - mx) : 0.f;
  float s = e0 + e1 + e2;
  for (int o = 32; o; o >>= 1) s += __shfl_down(s, o, 64);
  if ((t & 63) == 0) sm2[t >> 6] = s;
  __syncthreads();
  float inv = 1.f / (sm2[0] + sm2[1] + sm2[2] + sm2[3]);
  if (t < NS) a[t] = e0 * inv;
  if (t + 256 < NS) a[t + 256] = e1 * inv;
  if (t + 512 < NS) a[t + 512] = e2 * inv;
}

// ------- layernorm rows of v(bf16) -> bf16 vn; vectorized, regular loads -----
__global__ __launch_bounds__(256) void k_ln(const bf16* __restrict__ v,
                                            const float* __restrict__ lw,
                                            const float* __restrict__ lb,
                                            bf16* __restrict__ vn) {
  int r = blockIdx.x;
  int t = threadIdx.x;
  bf16x4* vn4 = (bf16x4*)(vn + (size_t)r * ND);
  if (r >= NM) {
    bf16x4 z;
    z[0] = (bf16)0.f; z[1] = (bf16)0.f; z[2] = (bf16)0.f; z[3] = (bf16)0.f;
    for (int i = t; i < NQ; i += 256) vn4[i] = z;
    return;
  }
  const bf16x4* row4 = (const bf16x4*)(v + (size_t)r * ND);
  bf16x4 b0 = row4[t];
  f32x4 x0 = {(float)b0[0], (float)b0[1], (float)b0[2], (float)b0[3]};
  f32x4 x1 = {0.f, 0.f, 0.f, 0.f};
  const bool has1 = (t + 256) < NQ;
  if (has1) {
    bf16x4 b1 = row4[t + 256];
    x1[0] = (float)b1[0]; x1[1] = (float)b1[1];
    x1[2] = (float)b1[2]; x1[3] = (float)b1[3];
  }
  float s = x0[0] + x0[1] + x0[2] + x0[3] + x1[0] + x1[1] + x1[2] + x1[3];
  float sq = x0[0] * x0[0] + x0[1] * x0[1] + x0[2] * x0[2] + x0[3] * x0[3] +
             x1[0] * x1[0] + x1[1] * x1[1] + x1[2] * x1[2] + x1[3] * x1[3];
  for (int o = 32; o; o >>= 1) {
    s += __shfl_down(s, o, 64);
    sq += __shfl_down(sq, o, 64);
  }
  __shared__ float smS[4], smQ[4];
  if ((t & 63) == 0) { smS[t >> 6] = s; smQ[t >> 6] = sq; }
  __syncthreads();
  s = smS[0] + smS[1] + smS[2] + smS[3];
  sq = smQ[0] + smQ[1] + smQ[2] + smQ[3];
  float mu = s * (1.f / ND);
  float var = sq * (1.f / ND) - mu * mu;
  float rstd = rsqrtf(var + LNEPS);
  const f32x4* lw4 = (const f32x4*)lw;
  const f32x4* lb4 = (const f32x4*)lb;
  {
    f32x4 wv = lw4[t], bv = lb4[t];
    bf16x4 o;
    o[0] = (bf16)((x0[0] - mu) * rstd * wv[0] + bv[0]);
    o[1] = (bf16)((x0[1] - mu) * rstd * wv[1] + bv[1]);
    o[2] = (bf16)((x0[2] - mu) * rstd * wv[2] + bv[2]);
    o[3] = (bf16)((x0[3] - mu) * rstd * wv[3] + bv[3]);
    vn4[t] = o;
  }
  if (has1) {
    f32x4 wv = lw4[t + 256], bv = lb4[t + 256];
    bf16x4 o;
    o[0] = (bf16)((x1[0] - mu) * rstd * wv[0] + bv[0]);
    o[1] = (bf16)((x1[1] - mu) * rstd * wv[1] + bv[1]);
    o[2] = (bf16)((x1[2] - mu) * rstd * wv[2] + bv[2]);
    o[3] = (bf16)((x1[3] - mu) * rstd * wv[3] + bv[3]);
    vn4[t + 256] = o;
  }
}

// ==== 128x256xBK32, 8-wave, 2 blocks/CU, 3-buffer counted-vmcnt GEMM ====
// R17: MODE 1 epilogue LDS-repack with CORRECTED lane-contiguous NT readback:
// lane l covers row w*2+(l>>5)+i*16, 16B chunk (l&31)*16 -> lanes 0-31 span
// 512B of one row contiguously; every 64B line written whole by one store
// instruction (R16's scattered mapping caused 3.6x partial-line writebacks).
// MODE 0 (vb) keeps plain cached stores (k_ln/fc2 consume it — R13 lesson).
template <int MODE>
__global__ __launch_bounds__(512, 4) void gemm128(const bf16* __restrict__ A,
                                                  const bf16* __restrict__ Bm,
                                                  const float* __restrict__ bias,
                                                  const bf16* __restrict__ resid,
                                                  float* __restrict__ Cf,
                                                  bf16* __restrict__ Cb,
                                                  int K, int Mreal, int Nreal,
                                                  int ldc, int gx, int G) {
  __shared__ bf16 lds[3][384 * 32];   // [buf][A:128 rows | B:256 rows][32 k]
  const int tid = threadIdx.x;
  const int w = tid >> 6, lane = tid & 63;

  // T1: bijective XCD-aware block swizzle (m204)
  const int nwg = gridDim.x;
  const int orig = blockIdx.x;
  const int qq = nwg >> 3, rr = nwg & 7;
  const int xcd = orig & 7, idx0 = orig >> 3;
  const int wgid = (xcd < rr ? xcd * (qq + 1) : rr * (qq + 1) + (xcd - rr) * qq) + idx0;

  // grouped decode: G rows per group, column-major within group (R13 best)
  const int gy = nwg / gx;
  const int full = (gy / G) * G * gx;
  int bx, by;
  if (wgid < full) {
    int g = wgid / (G * gx), r2 = wgid - g * (G * gx);
    bx = r2 / G; by = g * G + (r2 - bx * G);
  } else {
    int r2 = wgid - full;
    int base = (gy / G) * G, rows = gy - base;
    bx = r2 / rows; by = base + (r2 - bx * rows);
  }
  const int row0 = by * 128, col0 = bx * 256;

  // staging: wave w covers 16 rows (lane>>2), chunk lane&3 at LDS (linear);
  // global source chunk = (lane&3) ^ ((lane>>3)&3)
  const int laneRow = lane >> 2;
  const int laneChunk = (lane & 3) ^ ((lane >> 3) & 3);

  auto STAGE_A = [&](int buf, int kt) {   // A tile 128x32 = 8 KB, 1 load/thread
    const bf16* gp = A + (size_t)(row0 + w * 16 + laneRow) * K + kt * 32 + laneChunk * 8;
    GLOAD16(gp, &lds[buf][(w * 16) * 32]);
  };
  auto STAGE_B = [&](int buf, int u, int kt) {  // B half-tile 128x32 = 8 KB
    const bf16* gp = Bm + (size_t)(col0 + u * 128 + w * 16 + laneRow) * K + kt * 32 + laneChunk * 8;
    GLOAD16(gp, &lds[buf][4096 + (u * 128 + w * 16) * 32]);
  };

  // fragment addressing (16x16x32: row = fr, k-chunk = fq, swizzled)
  const int wm = w >> 2, wn = w & 3;
  const int fr = lane & 15, fq = lane >> 4;
  const int fsw = ((fq ^ ((fr >> 1) & 3)) << 3);   // swizzled k-offset (elems)
  const int arow = wm * 64 + fr;
  const int brow = wn * 64 + fr;

  f32x4 acc[4][4] = {};

  const int nk = K >> 5;
  // ---- prologue: tiles 0,1 staged; wait tile0 only (tile1 in flight) ----
  STAGE_A(0, 0); STAGE_B(0, 0, 0); STAGE_B(0, 1, 0);
  if (nk > 1) {
    STAGE_A(1, 1); STAGE_B(1, 0, 1); STAGE_B(1, 1, 1);
    asm volatile("s_waitcnt vmcnt(3)" ::: "memory");
  } else {
    asm volatile("s_waitcnt vmcnt(0)" ::: "memory");
  }
  __builtin_amdgcn_s_barrier();

  int cur = 0;
  for (int t = 0; t < nk; ++t) {
    const bf16* As = &lds[cur][0];
    const bf16* Bs = &lds[cur][4096];
    // issue tile t+2's staging into the buffer consumed at t-1
    if (t + 2 < nk) {
      int tgt = cur + 2; if (tgt >= 3) tgt -= 3;
      STAGE_A(tgt, t + 2);
      STAGE_B(tgt, 0, t + 2);
      STAGE_B(tgt, 1, t + 2);
    }
    bf16x8 bfr[4];
#pragma unroll
    for (int ni = 0; ni < 4; ++ni)
      bfr[ni] = *(const bf16x8*)(&Bs[(brow + ni * 16) * 32 + fsw]);
    __builtin_amdgcn_s_setprio(1);
#pragma unroll
    for (int mi = 0; mi < 4; ++mi) {
      bf16x8 af = *(const bf16x8*)(&As[(arow + mi * 16) * 32 + fsw]);
#pragma unroll
      for (int ni = 0; ni < 4; ++ni)
        acc[mi][ni] = __builtin_amdgcn_mfma_f32_16x16x32_bf16(af, bfr[ni],
                                                              acc[mi][ni], 0, 0, 0);
    }
    __builtin_amdgcn_s_setprio(0);
    if (t + 2 < nk)      { asm volatile("s_waitcnt vmcnt(3)" ::: "memory"); }
    else if (t + 1 < nk) { asm volatile("s_waitcnt vmcnt(0)" ::: "memory"); }
    __builtin_amdgcn_s_barrier();
    cur += 1; if (cur >= 3) cur -= 3;
  }

  // ---- epilogue ----
  const int rb = row0 + wm * 64, cb = col0 + wn * 64;
  if (MODE == 1) {
    // gelu -> LDS repack -> lane-contiguous full-line NT stores.
    bf16* ep = (bf16*)lds;            // 128 x 264 bf16 = 67.5 KB <= 72 KB
    __syncthreads();
#pragma unroll
    for (int mi = 0; mi < 4; ++mi) {
#pragma unroll
      for (int ni = 0; ni < 4; ++ni) {
        int cl = wn * 64 + ni * 16 + fr;        // block-local col
        int cg = col0 + cl;                     // global col
        float bb = (cg < Nreal) ? bias[cg] : 0.f;
#pragma unroll
        for (int j = 0; j < 4; ++j) {
          int rl = wm * 64 + mi * 16 + fq * 4 + j;  // block-local row
          float g = 0.f;
          if (cg < Nreal) {
            float x = acc[mi][ni][j] + bb;
            float z = 1.5957691216057308f * (x + 0.044715f * x * x * x);
            g = x / (1.f + __expf(-z));
          }
          ep[rl * EPS_STRIDE + cl] = (bf16)g;
        }
      }
    }
    __syncthreads();
    // readback: lane l -> row w*2 + (l>>5) + i*16, 16B chunk (l&31)*8 elems.
    // Lanes 0-31 cover 512B of one row contiguously -> full 64B lines/instr.
    int half = lane >> 5, lc = lane & 31;
#pragma unroll
    for (int i = 0; i < 8; ++i) {
      int rl = w * 2 + half + i * 16;
      const bf16* lsrc = &ep[rl * EPS_STRIDE + lc * 8];
      bf16* gdst = Cb + (size_t)(row0 + rl) * ldc + col0 + lc * 8;
      bf16x8 vv = *(const bf16x8*)lsrc;
      u32x4 uu;
      __builtin_memcpy(&uu, &vv, 16);
      __builtin_nontemporal_store(uu, (u32x4*)gdst);
    }
  } else {
#pragma unroll
    for (int mi = 0; mi < 4; ++mi) {
#pragma unroll
      for (int ni = 0; ni < 4; ++ni) {
        int c = cb + ni * 16 + fr;
#pragma unroll
        for (int j = 0; j < 4; ++j) {
          int r = rb + mi * 16 + fq * 4 + j;
          float v = acc[mi][ni][j];
          if (MODE == 0) {
            if (r < Mreal && c < Nreal)
              Cb[(size_t)r * ldc + c] = (bf16)(v + bias[c]);
          } else {
            if (r < Mreal && c < Nreal)
              nt_store_f32(v + bias[c] + (float)resid[(size_t)r * ldc + c],
                           &Cf[(size_t)r * ldc + c]);
          }
        }
      }
    }
  }
}

extern "C" void kernel_launch(void* const* d_in, const int* in_sizes, int n_in,
                              void* d_out, int out_size, void* d_ws, size_t ws_size,
                              hipStream_t stream) {
  const float* hs    = (const float*)d_in[0];
  const float* probe = (const float*)d_in[1];
  const float* ipw   = (const float*)d_in[2];
  const float* ipb   = (const float*)d_in[3];
  const float* lw    = (const float*)d_in[4];
  const float* lb    = (const float*)d_in[5];
  const float* fc1w  = (const float*)d_in[6];
  const float* fc1b  = (const float*)d_in[7];
  const float* fc2w  = (const float*)d_in[8];
  const float* fc2b  = (const float*)d_in[9];
  float* out  = (float*)d_out;
  float* attn = out + OUT0;

  char* ws = (char*)d_ws;
  size_t off = 0;
  auto alloc = [&](size_t bytes) {
    char* p = ws + off;
    off += (bytes + 255) & ~(size_t)255;
    return p;
  };
  float* q  = (float*)alloc((size_t)ND * 4);
  float* qk = (float*)alloc((size_t)NH * ND * 4);
  float* qb = (float*)alloc((size_t)NH * 4);
  bf16* hsb = (bf16*)alloc((size_t)MP * ND * 2);   // doubles as vnb after v-proj
  bf16* vb  = (bf16*)alloc((size_t)MP * ND * 2);   // v in bf16
  bf16* wvb = (bf16*)alloc((size_t)NDP * ND * 2);
  bf16* f1b = (bf16*)alloc((size_t)NIP * ND * 2);
  bf16* f2b = (bf16*)alloc((size_t)NDP * NIP * 2);
  bf16* h1b = (bf16*)alloc((size_t)MP * NIP * 2);
  bf16* vnb = hsb;   // alias: hsb is dead after v-proj; k_ln runs after

  // weight conversions to bf16 (zero-padded)
  k_conv_w<<<(NDP * (ND / 4) + 255) / 256, 256, 0, stream>>>(
      ipw + (size_t)2 * ND * ND, wvb, ND, ND, NDP, ND);
  k_conv_w<<<(NIP * (ND / 4) + 255) / 256, 256, 0, stream>>>(
      fc1w, f1b, NI, ND, NIP, ND);
  k_conv_w<<<(NDP * (NIP / 4) + 255) / 256, 256, 0, stream>>>(
      fc2w, f2b, ND, NI, NDP, NIP);

  // attention scores path (f32, exact) — k_scores also emits hsb (bf16,
  // rows >= NM zeroed in-kernel)
  k_q<<<ND, 256, 0, stream>>>(ipw, probe, ipb, q);
  k_qk<<<(NH * ND + 255) / 256, 256, 0, stream>>>(
      ipw + (size_t)ND * ND, ipb + ND, q, qk, qb);
  k_scores<<<MP, 256, 0, stream>>>(hs, qk, qb, attn, hsb);
  k_softmax<<<NB * NH, 256, 0, stream>>>(attn);

  // v = hs @ Wv^T + bv  -> bf16 vb          (grid 92x5, G=8 row groups)
  gemm128<0><<<(MP / 128) * (NDP / 256), 512, 0, stream>>>(
      hsb, wvb, ipb + 2 * ND, nullptr, nullptr, vb, ND, NM, ND, ND,
      NDP / 256, 8);
  // vn = LN(vb) -> bf16 (into hsb's buffer)
  k_ln<<<MP, 256, 0, stream>>>(vb, lw, lb, vnb);
  // h1 = gelu(vn @ fc1^T + b1) -> bf16      (grid 92x17, G=8)
  gemm128<1><<<(MP / 128) * (NIP / 256), 512, 0, stream>>>(
      vnb, f1b, fc1b, nullptr, nullptr, h1b, ND, MP, NI, NIP, NIP / 256, 8);
  // out = vb + h1 @ fc2^T + b2              (grid 92x5, G=2)
  gemm128<2><<<(MP / 128) * (NDP / 256), 512, 0, stream>>>(
      h1b, f2b, fc2b, vb, out, nullptr, NIP, NM, ND, ND, NDP / 256, 2);
}

// Round 18
// 450.862 us; speedup vs baseline: 1.3651x; 1.0380x over previous
//
#include <hip/hip_runtime.h>
#include <hip/hip_bf16.h>

typedef __bf16 bf16;
typedef __bf16 bf16x4 __attribute__((ext_vector_type(4)));
typedef __bf16 bf16x8 __attribute__((ext_vector_type(8)));
typedef float f32x4 __attribute__((ext_vector_type(4)));

#define NB 16
#define NS 729
#define ND 1152
#define NDP 1280        /* 5*256: padded N for v-proj / fc2 outputs */
#define NH 16
#define NHD 72
#define NI 4304
#define NM (NB*NS)      /* 11664 */
#define MP 11776        /* 92*128 */
#define NIP 4352        /* 17*256 */
#define NQ (ND/4)       /* 288 quads per row */
#define OUT0 ((size_t)NM*(size_t)ND)
#define LNEPS 1e-6f

#define GLOAD16(gp, lp) __builtin_amdgcn_global_load_lds( \
    (const __attribute__((address_space(1))) void*)(gp),  \
    (__attribute__((address_space(3))) void*)(lp), 16, 0, 0)

static __device__ __forceinline__ void nt_store_f32(float v, float* p) {
  __builtin_nontemporal_store(v, p);
}

// ---------------- weight conversions ----------------
__global__ __launch_bounds__(256) void k_conv_w(const float* __restrict__ src,
                                                bf16* __restrict__ dst,
                                                int sR, int sC, int dR, int dC) {
  int idx = blockIdx.x * 256 + threadIdx.x;
  int rowlen = dC >> 2;
  int r = idx / rowlen;
  int c = (idx - r * rowlen) * 4;
  if (r >= dR) return;
  bf16x4 o;
  if (r < sR && c + 4 <= sC) {
    float4 v = *(const float4*)(&src[(size_t)r * sC + c]);
    o[0] = (bf16)v.x; o[1] = (bf16)v.y; o[2] = (bf16)v.z; o[3] = (bf16)v.w;
  } else {
    o[0] = (bf16)0.f; o[1] = (bf16)0.f; o[2] = (bf16)0.f; o[3] = (bf16)0.f;
  }
  *(bf16x4*)(&dst[(size_t)r * dC + c]) = o;
}

// ---------------- q = Wq @ probe + bq ----------------
__global__ __launch_bounds__(256) void k_q(const float* __restrict__ Wq,
                                           const float* __restrict__ probe,
                                           const float* __restrict__ bq,
                                           float* __restrict__ q) {
  int d = blockIdx.x;
  const float* wrow = Wq + (size_t)d * ND;
  float s = 0.f;
  for (int e = threadIdx.x; e < ND; e += 256) s += wrow[e] * probe[e];
  for (int o = 32; o; o >>= 1) s += __shfl_down(s, o, 64);
  __shared__ float sm[4];
  if ((threadIdx.x & 63) == 0) sm[threadIdx.x >> 6] = s;
  __syncthreads();
  if (threadIdx.x == 0) q[d] = sm[0] + sm[1] + sm[2] + sm[3] + bq[d];
}

// ---------------- qk[h,e] = sum_j q[h*72+j]*Wk[h*72+j, e]  (scaled) ----------------
__global__ __launch_bounds__(256) void k_qk(const float* __restrict__ Wk,
                                            const float* __restrict__ bk,
                                            const float* __restrict__ q,
                                            float* __restrict__ qk,
                                            float* __restrict__ qb) {
  int idx = blockIdx.x * 256 + threadIdx.x;
  if (idx >= NH * ND) return;
  int h = idx / ND, e = idx - h * ND;
  const float scale = 0.11785113019775793f;  // 1/sqrt(72)
  float s = 0.f;
  for (int j = 0; j < NHD; ++j)
    s += q[h * NHD + j] * Wk[(size_t)(h * NHD + j) * ND + e];
  qk[idx] = s * scale;
  if (e == 0) {
    float sb = 0.f;
    for (int j = 0; j < NHD; ++j) sb += q[h * NHD + j] * bk[h * NHD + j];
    qb[h] = sb * scale;
  }
}

// ------- scores[b,h,s] = hs[b,s,:]·qk[h,:] + qb[h]; also emit hsb (bf16) -------
__global__ __launch_bounds__(256) void k_scores(const float* __restrict__ hs,
                                                const float* __restrict__ qk,
                                                const float* __restrict__ qb,
                                                float* __restrict__ attn,
                                                bf16* __restrict__ hsb) {
  int p = blockIdx.x;                 // (b*S + s)
  int t = threadIdx.x;
  bf16x4* orow4 = (bf16x4*)(hsb + (size_t)p * ND);
  if (p >= NM) {
    bf16x4 z;
    z[0] = (bf16)0.f; z[1] = (bf16)0.f; z[2] = (bf16)0.f; z[3] = (bf16)0.f;
    for (int i = t; i < NQ; i += 256) orow4[i] = z;
    return;
  }
  const f32x4* row4 = (const f32x4*)(hs + (size_t)p * ND);
  const f32x4* qk4 = (const f32x4*)qk;
  float acc[NH];
#pragma unroll
  for (int h = 0; h < NH; ++h) acc[h] = 0.f;
  for (int i = t; i < NQ; i += 256) {
    f32x4 x = __builtin_nontemporal_load(&row4[i]);
    bf16x4 o;
    o[0] = (bf16)x[0]; o[1] = (bf16)x[1]; o[2] = (bf16)x[2]; o[3] = (bf16)x[3];
    orow4[i] = o;
#pragma unroll
    for (int h = 0; h < NH; ++h) {
      f32x4 wv = qk4[h * NQ + i];
      acc[h] = fmaf(x[0], wv[0],
               fmaf(x[1], wv[1], fmaf(x[2], wv[2], fmaf(x[3], wv[3], acc[h]))));
    }
  }
  __shared__ float part[NH][257];
#pragma unroll
  for (int h = 0; h < NH; ++h) part[h][t] = acc[h];
  __syncthreads();
  int h = t >> 4, l = t & 15;
  float s = 0.f;
#pragma unroll
  for (int k = 0; k < 16; ++k) s += part[h][l + k * 16];
#pragma unroll
  for (int o = 8; o; o >>= 1) s += __shfl_xor(s, o, 16);
  if (l == 0) {
    int b = p / NS, si = p - b * NS;
    attn[((size_t)(b * NH + h)) * NS + si] = s + qb[h];
  }
}

// ---------------- softmax over S for each (b,h) row, in place ----------------
__global__ __launch_bounds__(256) void k_softmax(float* __restrict__ attn) {
  float* a = attn + (size_t)blockIdx.x * NS;
  int t = threadIdx.x;
  float x0 = (t < NS) ? a[t] : -1e30f;
  float x1 = (t + 256 < NS) ? a[t + 256] : -1e30f;
  float x2 = (t + 512 < NS) ? a[t + 512] : -1e30f;
  float mx = fmaxf(x0, fmaxf(x1, x2));
  for (int o = 32; o; o >>= 1) mx = fmaxf(mx, __shfl_down(mx, o, 64));
  __shared__ float sm[4], sm2[4];
  if ((t & 63) == 0) sm[t >> 6] = mx;
  __syncthreads();
  mx = fmaxf(fmaxf(sm[0], sm[1]), fmaxf(sm[2], sm[3]));
  float e0 = (t < NS) ? __expf(x0 - mx) : 0.f;
  float e1 = (t + 256 < NS) ? __expf(x1 - mx) : 0.f;
  float e2 = (t + 512 < NS) ? __expf(x2 - mx) : 0.f;
  float s = e0 + e1 + e2;
  for (int o = 32; o; o >>= 1) s += __shfl_down(s, o, 64);
  if ((t & 63) == 0) sm2[t >> 6] = s;
  __syncthreads();
  float inv = 1.f / (sm2[0] + sm2[1] + sm2[2] + sm2[3]);
  if (t < NS) a[t] = e0 * inv;
  if (t + 256 < NS) a[t + 256] = e1 * inv;
  if (t + 512 < NS) a[t + 512] = e2 * inv;
}

// ------- layernorm rows of v(bf16) -> bf16 vn; vectorized, regular loads -----
__global__ __launch_bounds__(256) void k_ln(const bf16* __restrict__ v,
                                            const float* __restrict__ lw,
                                            const float* __restrict__ lb,
                                            bf16* __restrict__ vn) {
  int r = blockIdx.x;
  int t = threadIdx.x;
  bf16x4* vn4 = (bf16x4*)(vn + (size_t)r * ND);
  if (r >= NM) {
    bf16x4 z;
    z[0] = (bf16)0.f; z[1] = (bf16)0.f; z[2] = (bf16)0.f; z[3] = (bf16)0.f;
    for (int i = t; i < NQ; i += 256) vn4[i] = z;
    return;
  }
  const bf16x4* row4 = (const bf16x4*)(v + (size_t)r * ND);
  bf16x4 b0 = row4[t];
  f32x4 x0 = {(float)b0[0], (float)b0[1], (float)b0[2], (float)b0[3]};
  f32x4 x1 = {0.f, 0.f, 0.f, 0.f};
  const bool has1 = (t + 256) < NQ;
  if (has1) {
    bf16x4 b1 = row4[t + 256];
    x1[0] = (float)b1[0]; x1[1] = (float)b1[1];
    x1[2] = (float)b1[2]; x1[3] = (float)b1[3];
  }
  float s = x0[0] + x0[1] + x0[2] + x0[3] + x1[0] + x1[1] + x1[2] + x1[3];
  float sq = x0[0] * x0[0] + x0[1] * x0[1] + x0[2] * x0[2] + x0[3] * x0[3] +
             x1[0] * x1[0] + x1[1] * x1[1] + x1[2] * x1[2] + x1[3] * x1[3];
  for (int o = 32; o; o >>= 1) {
    s += __shfl_down(s, o, 64);
    sq += __shfl_down(sq, o, 64);
  }
  __shared__ float smS[4], smQ[4];
  if ((t & 63) == 0) { smS[t >> 6] = s; smQ[t >> 6] = sq; }
  __syncthreads();
  s = smS[0] + smS[1] + smS[2] + smS[3];
  sq = smQ[0] + smQ[1] + smQ[2] + smQ[3];
  float mu = s * (1.f / ND);
  float var = sq * (1.f / ND) - mu * mu;
  float rstd = rsqrtf(var + LNEPS);
  const f32x4* lw4 = (const f32x4*)lw;
  const f32x4* lb4 = (const f32x4*)lb;
  {
    f32x4 wv = lw4[t], bv = lb4[t];
    bf16x4 o;
    o[0] = (bf16)((x0[0] - mu) * rstd * wv[0] + bv[0]);
    o[1] = (bf16)((x0[1] - mu) * rstd * wv[1] + bv[1]);
    o[2] = (bf16)((x0[2] - mu) * rstd * wv[2] + bv[2]);
    o[3] = (bf16)((x0[3] - mu) * rstd * wv[3] + bv[3]);
    vn4[t] = o;
  }
  if (has1) {
    f32x4 wv = lw4[t + 256], bv = lb4[t + 256];
    bf16x4 o;
    o[0] = (bf16)((x1[0] - mu) * rstd * wv[0] + bv[0]);
    o[1] = (bf16)((x1[1] - mu) * rstd * wv[1] + bv[1]);
    o[2] = (bf16)((x1[2] - mu) * rstd * wv[2] + bv[2]);
    o[3] = (bf16)((x1[3] - mu) * rstd * wv[3] + bv[3]);
    vn4[t + 256] = o;
  }
}

// ==== 128x256xBK32, 8-wave, 2 blocks/CU, 3-buffer counted-vmcnt GEMM ====
// R18 = exact revert to R15 (best measured: 451 us). Epilogues:
// MODE 0: Cb = (bf16)(acc + bias)   (plain stores -> cached for k_ln/fc2)
// MODE 1: Cb = gelu(acc + bias)     (bf16, plain stores -> cached for fc2;
//         NT here measured -20 us on fc2, R17)
// MODE 2: Cf = acc + bias + (float)resid_bf16   (NT f32 stores, dead stream)
template <int MODE>
__global__ __launch_bounds__(512, 4) void gemm128(const bf16* __restrict__ A,
                                                  const bf16* __restrict__ Bm,
                                                  const float* __restrict__ bias,
                                                  const bf16* __restrict__ resid,
                                                  float* __restrict__ Cf,
                                                  bf16* __restrict__ Cb,
                                                  int K, int Mreal, int Nreal,
                                                  int ldc, int gx, int G) {
  __shared__ bf16 lds[3][384 * 32];   // [buf][A:128 rows | B:256 rows][32 k]
  const int tid = threadIdx.x;
  const int w = tid >> 6, lane = tid & 63;

  // T1: bijective XCD-aware block swizzle (m204)
  const int nwg = gridDim.x;
  const int orig = blockIdx.x;
  const int qq = nwg >> 3, rr = nwg & 7;
  const int xcd = orig & 7, idx0 = orig >> 3;
  const int wgid = (xcd < rr ? xcd * (qq + 1) : rr * (qq + 1) + (xcd - rr) * qq) + idx0;

  // grouped decode: G rows per group, column-major within group
  const int gy = nwg / gx;
  const int full = (gy / G) * G * gx;
  int bx, by;
  if (wgid < full) {
    int g = wgid / (G * gx), r2 = wgid - g * (G * gx);
    bx = r2 / G; by = g * G + (r2 - bx * G);
  } else {
    int r2 = wgid - full;
    int base = (gy / G) * G, rows = gy - base;
    bx = r2 / rows; by = base + (r2 - bx * rows);
  }
  const int row0 = by * 128, col0 = bx * 256;

  // staging: wave w covers 16 rows (lane>>2), chunk lane&3 at LDS (linear);
  // global source chunk = (lane&3) ^ ((lane>>3)&3)
  const int laneRow = lane >> 2;
  const int laneChunk = (lane & 3) ^ ((lane >> 3) & 3);

  auto STAGE_A = [&](int buf, int kt) {   // A tile 128x32 = 8 KB, 1 load/thread
    const bf16* gp = A + (size_t)(row0 + w * 16 + laneRow) * K + kt * 32 + laneChunk * 8;
    GLOAD16(gp, &lds[buf][(w * 16) * 32]);
  };
  auto STAGE_B = [&](int buf, int u, int kt) {  // B half-tile 128x32 = 8 KB
    const bf16* gp = Bm + (size_t)(col0 + u * 128 + w * 16 + laneRow) * K + kt * 32 + laneChunk * 8;
    GLOAD16(gp, &lds[buf][4096 + (u * 128 + w * 16) * 32]);
  };

  // fragment addressing (16x16x32: row = fr, k-chunk = fq, swizzled)
  const int wm = w >> 2, wn = w & 3;
  const int fr = lane & 15, fq = lane >> 4;
  const int fsw = ((fq ^ ((fr >> 1) & 3)) << 3);   // swizzled k-offset (elems)
  const int arow = wm * 64 + fr;
  const int brow = wn * 64 + fr;

  f32x4 acc[4][4] = {};

  const int nk = K >> 5;
  // ---- prologue: tiles 0,1 staged; wait tile0 only (tile1 in flight) ----
  STAGE_A(0, 0); STAGE_B(0, 0, 0); STAGE_B(0, 1, 0);
  if (nk > 1) {
    STAGE_A(1, 1); STAGE_B(1, 0, 1); STAGE_B(1, 1, 1);
    asm volatile("s_waitcnt vmcnt(3)" ::: "memory");
  } else {
    asm volatile("s_waitcnt vmcnt(0)" ::: "memory");
  }
  __builtin_amdgcn_s_barrier();

  int cur = 0;
  for (int t = 0; t < nk; ++t) {
    const bf16* As = &lds[cur][0];
    const bf16* Bs = &lds[cur][4096];
    // issue tile t+2's staging into the buffer consumed at t-1
    if (t + 2 < nk) {
      int tgt = cur + 2; if (tgt >= 3) tgt -= 3;
      STAGE_A(tgt, t + 2);
      STAGE_B(tgt, 0, t + 2);
      STAGE_B(tgt, 1, t + 2);
    }
    bf16x8 bfr[4];
#pragma unroll
    for (int ni = 0; ni < 4; ++ni)
      bfr[ni] = *(const bf16x8*)(&Bs[(brow + ni * 16) * 32 + fsw]);
    __builtin_amdgcn_s_setprio(1);
#pragma unroll
    for (int mi = 0; mi < 4; ++mi) {
      bf16x8 af = *(const bf16x8*)(&As[(arow + mi * 16) * 32 + fsw]);
#pragma unroll
      for (int ni = 0; ni < 4; ++ni)
        acc[mi][ni] = __builtin_amdgcn_mfma_f32_16x16x32_bf16(af, bfr[ni],
                                                              acc[mi][ni], 0, 0, 0);
    }
    __builtin_amdgcn_s_setprio(0);
    if (t + 2 < nk)      { asm volatile("s_waitcnt vmcnt(3)" ::: "memory"); }
    else if (t + 1 < nk) { asm volatile("s_waitcnt vmcnt(0)" ::: "memory"); }
    __builtin_amdgcn_s_barrier();
    cur += 1; if (cur >= 3) cur -= 3;
  }

  // ---- epilogue: C col = lane&15, row = (lane>>4)*4+j ----
  const int rb = row0 + wm * 64, cb = col0 + wn * 64;
#pragma unroll
  for (int mi = 0; mi < 4; ++mi) {
#pragma unroll
    for (int ni = 0; ni < 4; ++ni) {
      int c = cb + ni * 16 + fr;
#pragma unroll
      for (int j = 0; j < 4; ++j) {
        int r = rb + mi * 16 + fq * 4 + j;
        float v = acc[mi][ni][j];
        if (MODE == 0) {
          if (r < Mreal && c < Nreal)
            Cb[(size_t)r * ldc + c] = (bf16)(v + bias[c]);
        } else if (MODE == 1) {
          float g = 0.f;
          if (c < Nreal) {
            float x = v + bias[c];
            // gelu_tanh(x) == x * sigmoid(2*0.7978845608*(x + 0.044715 x^3))
            float z = 1.5957691216057308f * (x + 0.044715f * x * x * x);
            g = x / (1.f + __expf(-z));
          }
          Cb[(size_t)r * ldc + c] = (bf16)g;
        } else {
          if (r < Mreal && c < Nreal)
            nt_store_f32(v + bias[c] + (float)resid[(size_t)r * ldc + c],
                         &Cf[(size_t)r * ldc + c]);
        }
      }
    }
  }
}

extern "C" void kernel_launch(void* const* d_in, const int* in_sizes, int n_in,
                              void* d_out, int out_size, void* d_ws, size_t ws_size,
                              hipStream_t stream) {
  const float* hs    = (const float*)d_in[0];
  const float* probe = (const float*)d_in[1];
  const float* ipw   = (const float*)d_in[2];
  const float* ipb   = (const float*)d_in[3];
  const float* lw    = (const float*)d_in[4];
  const float* lb    = (const float*)d_in[5];
  const float* fc1w  = (const float*)d_in[6];
  const float* fc1b  = (const float*)d_in[7];
  const float* fc2w  = (const float*)d_in[8];
  const float* fc2b  = (const float*)d_in[9];
  float* out  = (float*)d_out;
  float* attn = out + OUT0;

  char* ws = (char*)d_ws;
  size_t off = 0;
  auto alloc = [&](size_t bytes) {
    char* p = ws + off;
    off += (bytes + 255) & ~(size_t)255;
    return p;
  };
  float* q  = (float*)alloc((size_t)ND * 4);
  float* qk = (float*)alloc((size_t)NH * ND * 4);
  float* qb = (float*)alloc((size_t)NH * 4);
  bf16* hsb = (bf16*)alloc((size_t)MP * ND * 2);   // doubles as vnb after v-proj
  bf16* vb  = (bf16*)alloc((size_t)MP * ND * 2);   // v in bf16
  bf16* wvb = (bf16*)alloc((size_t)NDP * ND * 2);
  bf16* f1b = (bf16*)alloc((size_t)NIP * ND * 2);
  bf16* f2b = (bf16*)alloc((size_t)NDP * NIP * 2);
  bf16* h1b = (bf16*)alloc((size_t)MP * NIP * 2);
  bf16* vnb = hsb;   // alias: hsb is dead after v-proj; k_ln runs after

  // weight conversions to bf16 (zero-padded)
  k_conv_w<<<(NDP * (ND / 4) + 255) / 256, 256, 0, stream>>>(
      ipw + (size_t)2 * ND * ND, wvb, ND, ND, NDP, ND);
  k_conv_w<<<(NIP * (ND / 4) + 255) / 256, 256, 0, stream>>>(
      fc1w, f1b, NI, ND, NIP, ND);
  k_conv_w<<<(NDP * (NIP / 4) + 255) / 256, 256, 0, stream>>>(
      fc2w, f2b, ND, NI, NDP, NIP);

  // attention scores path (f32, exact) — k_scores also emits hsb (bf16,
  // rows >= NM zeroed in-kernel)
  k_q<<<ND, 256, 0, stream>>>(ipw, probe, ipb, q);
  k_qk<<<(NH * ND + 255) / 256, 256, 0, stream>>>(
      ipw + (size_t)ND * ND, ipb + ND, q, qk, qb);
  k_scores<<<MP, 256, 0, stream>>>(hs, qk, qb, attn, hsb);
  k_softmax<<<NB * NH, 256, 0, stream>>>(attn);

  // v = hs @ Wv^T + bv  -> bf16 vb          (grid 92x5, G=8 row groups)
  gemm128<0><<<(MP / 128) * (NDP / 256), 512, 0, stream>>>(
      hsb, wvb, ipb + 2 * ND, nullptr, nullptr, vb, ND, NM, ND, ND,
      NDP / 256, 8);
  // vn = LN(vb) -> bf16 (into hsb's buffer)
  k_ln<<<MP, 256, 0, stream>>>(vb, lw, lb, vnb);
  // h1 = gelu(vn @ fc1^T + b1) -> bf16      (grid 92x17, G=8)
  gemm128<1><<<(MP / 128) * (NIP / 256), 512, 0, stream>>>(
      vnb, f1b, fc1b, nullptr, nullptr, h1b, ND, MP, NI, NIP, NIP / 256, 8);
  // out = vb + h1 @ fc2^T + b2              (grid 92x5, G=2)
  gemm128<2><<<(MP / 128) * (NDP / 256), 512, 0, stream>>>(
      h1b, f2b, fc2b, vb, out, nullptr, NIP, NM, ND, ND, NDP / 256, 2);
}